// Round 4
// baseline (1519.292 us; speedup 1.0000x reference)
//
#include <hip/hip_runtime.h>
#include <hip/hip_cooperative_groups.h>
#include <stdint.h>

namespace cg = cooperative_groups;

#define TT   500
#define BB   64
#define IND  256
#define HD   512
#define OD   35
#define ROWS (TT*BB)   // 32000

typedef __attribute__((ext_vector_type(4))) int i32x4;

// fp32 scale exactly as numpy computes it
#define SCALE_F ((float)((1.0 - 0.001) / 31.0))

__device__ __forceinline__ void load16_lds(const int8_t* g, int8_t* l) {
  __builtin_amdgcn_global_load_lds((const __attribute__((address_space(1))) void*)g,
                                   (__attribute__((address_space(3))) void*)l, 16, 0, 0);
}

// ================================================================ shared device pieces

// ---- GEMM tile sweep: 128x128 tiles (4 waves, 64x64 each), BK=128 i8 bytes,
// global_load_lds width-16 staging, XOR bank swizzle (slot = chunk ^ (row&7)),
// exact integer i8 MFMA, i32 accum. XCD-chunked tile swizzle when ntiles%8==0.
__device__ __forceinline__ void gemm_tiles(const int8_t* A, const int8_t* B,
                                           uint16_t* M, int KB, int Hp,
                                           int coltiles, int ntiles,
                                           int8_t* As, int8_t* Bs) {
  int tid  = threadIdx.x;
  int lane = tid & 63, w = tid >> 6;
  int wr = (w >> 1) * 64, wc = (w & 1) * 64;   // wave's 64x64 subtile
  int lr = lane & 15, kgf = lane >> 4;
  for (int t0 = blockIdx.x; t0 < ntiles; t0 += gridDim.x) {
    int bid = t0;
    if (!(ntiles & 7)) bid = (t0 & 7) * (ntiles >> 3) + (t0 >> 3);   // bijective
    int rt = bid / coltiles, ct = bid - rt * coltiles;
    int r0 = rt * 128, c0 = ct * 128;
    i32x4 acc[4][4];
#pragma unroll
    for (int i = 0; i < 4; ++i)
#pragma unroll
      for (int j = 0; j < 4; ++j) acc[i][j] = (i32x4){0, 0, 0, 0};

    for (int k0 = 0; k0 < KB; k0 += 128) {
      __syncthreads();   // previous ds_reads complete before overwrite
#pragma unroll
      for (int i = 0; i < 4; ++i) {
        int L = i * 256 + tid;          // 16-B chunk index
        int row = L >> 3, c = L & 7;
        int kg = c ^ (row & 7);         // slot c stores global chunk kg
        load16_lds(A + (size_t)(r0 + row) * KB + k0 + kg * 16,
                   &As[(i * 256 + w * 64) * 16]);
      }
#pragma unroll
      for (int i = 0; i < 4; ++i) {
        int L = i * 256 + tid;
        int row = L >> 3, c = L & 7;
        int kg = c ^ (row & 7);
        load16_lds(B + (size_t)(c0 + row) * KB + k0 + kg * 16,
                   &Bs[(i * 256 + w * 64) * 16]);
      }
      __syncthreads();   // staged data visible (drains vmcnt)
#pragma unroll
      for (int kk = 0; kk < 2; ++kk) {
        i32x4 a[4], b[4];
#pragma unroll
        for (int s = 0; s < 4; ++s) {
          int arow = wr + s * 16 + lr;
          int sa   = (kk * 4 + kgf) ^ (arow & 7);
          a[s] = *(const i32x4*)&As[arow * 128 + sa * 16];
          int brow = wc + s * 16 + lr;
          int sb   = (kk * 4 + kgf) ^ (brow & 7);
          b[s] = *(const i32x4*)&Bs[brow * 128 + sb * 16];
        }
#pragma unroll
        for (int ar = 0; ar < 4; ++ar)
#pragma unroll
          for (int cs = 0; cs < 4; ++cs)
            acc[ar][cs] = __builtin_amdgcn_mfma_i32_16x16x64_i8(a[ar], b[cs], acc[ar][cs], 0, 0, 0);
      }
    }
    // C/D layout: col = lane&15, row = (lane>>4)*4 + reg
    int oc = lane & 15;
    int rb = (lane >> 4) * 4;
#pragma unroll
    for (int ar = 0; ar < 4; ++ar)
#pragma unroll
      for (int i = 0; i < 4; ++i) {
        size_t rowoff = (size_t)(r0 + wr + ar * 16 + rb + i) * Hp;
#pragma unroll
        for (int cs = 0; cs < 4; ++cs)
          __builtin_nontemporal_store((uint16_t)acc[ar][cs][i],
                                      &M[rowoff + c0 + wc + cs * 16 + oc]);
      }
  }
}

// ---- per-wave 64x64 naive i8 GEMM tile (layer 4), KB=512, Hp=64, c0=0
__device__ __forceinline__ void gemm64(const int8_t* A, const int8_t* B,
                                       uint16_t* M, int r0, int lane) {
  const int KB = 512, Hp = 64;
  int lr = lane & 15;
  int lk = (lane >> 4) * 16;
  const int8_t* ap = A + (size_t)(r0 + lr) * KB + lk;
  const int8_t* bp = B + (size_t)lr * KB + lk;
  i32x4 acc[4][4];
#pragma unroll
  for (int i = 0; i < 4; ++i)
#pragma unroll
    for (int j = 0; j < 4; ++j) acc[i][j] = (i32x4){0, 0, 0, 0};
#pragma unroll 2
  for (int k = 0; k < KB / 64; ++k) {
    i32x4 a[4], b[4];
#pragma unroll
    for (int s = 0; s < 4; ++s) {
      a[s] = *(const i32x4*)(ap + (size_t)s * 16 * KB + k * 64);
      b[s] = *(const i32x4*)(bp + (size_t)s * 16 * KB + k * 64);
    }
#pragma unroll
    for (int ar = 0; ar < 4; ++ar)
#pragma unroll
      for (int cs = 0; cs < 4; ++cs)
        acc[ar][cs] = __builtin_amdgcn_mfma_i32_16x16x64_i8(a[ar], b[cs], acc[ar][cs], 0, 0, 0);
  }
  int oc = lane & 15;
  int rb = (lane >> 4) * 4;
#pragma unroll
  for (int ar = 0; ar < 4; ++ar)
#pragma unroll
    for (int i = 0; i < 4; ++i) {
      size_t rowoff = (size_t)(r0 + ar * 16 + rb + i) * Hp;
#pragma unroll
      for (int cs = 0; cs < 4; ++cs)
        M[rowoff + cs * 16 + oc] = (uint16_t)acc[ar][cs][i];
    }
}

// ---- LIF scan column: np-exact fp32 recurrence, 3-deep software pipeline.
template<int H, int Hp, bool WS, bool WM, bool WN>
__device__ __forceinline__ void scan_col(int b, int h, bool lane0,
                                         const uint16_t* M, const int* nrow,
                                         const float* pbeta, float* spk_out,
                                         int8_t* s_out, int* n_out,
                                         float* mem_out) {
  int tid = b * H + h;
  float beta = fminf(1.0f, fmaxf(0.0f, *pbeta));
  const double DSCALE = (double)SCALE_F;
  const double DWMIN  = (double)0.001f;
  float mem = 0.0f;
  const uint16_t* Mp = M + (size_t)b * Hp + h;
  const int*      np = nrow + b;
  uint16_t mA[10], mB[10], mC[10]; int nA[10], nB[10], nC[10];

#define LOADBLK(mv, nv, G)                                                   \
  { int T0 = (G) * 10;                                                       \
    _Pragma("unroll") for (int j = 0; j < 10; ++j) {                         \
      mv[j] = __builtin_nontemporal_load(Mp + (size_t)(T0 + j) * (BB * Hp)); \
      nv[j] = np[(T0 + j) * BB]; } }

#define STEPBLK(mv, nv, G)                                                   \
  { int T0 = (G) * 10;                                                       \
    _Pragma("unroll") for (int j = 0; j < 10; ++j) {                         \
      int t = T0 + j; int row = t * BB + b;                                  \
      float cur = (float)((double)mv[j] * DSCALE + (double)nv[j] * DWMIN);   \
      int   rs  = (mem > 1.0f);                                              \
      float t2  = __fadd_rn(__fmul_rn(beta, mem), cur);                      \
      mem = rs ? __fsub_rn(t2, 1.0f) : t2;                                   \
      int spk = (mem > 1.0f);                                                \
      __builtin_nontemporal_store(spk ? 1.0f : 0.0f,                         \
                                  &spk_out[(size_t)t * (BB * H) + tid]);     \
      if (WS) s_out[(size_t)row * H + h] = (int8_t)spk;                      \
      if (WN) { unsigned long long bal = __ballot(spk);                      \
                if (lane0) atomicAdd(n_out + row, (int)__popcll(bal)); }     \
      if (WM) __builtin_nontemporal_store(mem,                               \
                                  &mem_out[(size_t)t * (BB * H) + tid]); } }

  LOADBLK(mA, nA, 0)
  LOADBLK(mB, nB, 1)
  for (int g = 0; g < 48; g += 3) {      // 50 blocks of 10: 16x3 + 2 epilogue
    LOADBLK(mC, nC, g + 2)
    STEPBLK(mA, nA, g)
    LOADBLK(mA, nA, g + 3)
    STEPBLK(mB, nB, g + 1)
    LOADBLK(mB, nB, g + 4)
    STEPBLK(mC, nC, g + 2)
  }
  STEPBLK(mA, nA, 48)
  STEPBLK(mB, nB, 49)
#undef LOADBLK
#undef STEPBLK
}

// ================================================================ fused cooperative kernel
// 1024 blocks x 256 threads, 4 blocks/CU resident (co-residency required for grid.sync).
// Phases: [prep||cochlea] g1 s1 g2 s2 g3 s3 g4 s4, separated by grid.sync().
__global__ __launch_bounds__(256, 4) void k_fused(
    const float* __restrict__ x, const float* __restrict__ Wch,
    const float* __restrict__ cbetas,
    const float* __restrict__ W1, const float* __restrict__ W2,
    const float* __restrict__ W3, const float* __restrict__ W4,
    const float* __restrict__ b1, const float* __restrict__ b2,
    const float* __restrict__ b3, const float* __restrict__ b4,
    int8_t* wk1, int8_t* wk2, int8_t* wk3, int8_t* wk4,
    int8_t* chs, int8_t* sbuf, uint16_t* mbuf,
    int* n_ch, int* n1, int* n2, int* n3,
    float* spk1, float* spk2, float* spk3, float* spk4, float* mem4) {
  __shared__ __align__(16) int8_t As[16384];
  __shared__ __align__(16) int8_t Bs[16384];
  cg::grid_group grid = cg::this_grid();
  int gwave = blockIdx.x * 4 + (threadIdx.x >> 6);
  int lane  = threadIdx.x & 63;
  bool lane0 = (lane == 0);

  // ---------------- P0: cochlea (blocks 0..63) || prep + counter-zero (rest)
  if (blockIdx.x < 64) {
    float* xs = (float*)As;
    int b = blockIdx.x;
    for (int t = threadIdx.x; t < TT; t += 256) {
      n_ch[t * BB + b] = 0;              // this block exclusively owns rows == b (mod 64)
      xs[t] = x[b * TT + t];
    }
    __syncthreads();
    int i = threadIdx.x;
    float w    = Wch[i];
    float beta = fminf(1.0f, fmaxf(0.0f, cbetas[i]));
    float mem  = 0.0f;
    for (int t = 0; t < TT; ++t) {
      float cur = __fmul_rn(xs[t], w);
      int   rs  = (mem > 1.0f);
      float t2  = __fadd_rn(__fmul_rn(beta, mem), cur);
      mem = rs ? __fsub_rn(t2, 1.0f) : t2;
      int spk = (mem > 1.0f);
      int row = t * BB + b;
      chs[(size_t)row * IND + i] = (int8_t)spk;
      unsigned long long bal = __ballot(spk);
      if (lane0) atomicAdd(n_ch + row, (int)__popcll(bal));
    }
  } else {
    int pid     = (blockIdx.x - 64) * 256 + threadIdx.x;
    int pstride = (gridDim.x - 64) * 256;
    for (int i = pid; i < 96000; i += pstride) n1[i] = 0;   // n1,n2,n3 contiguous
    for (int id = pid; id < 688128; id += pstride) {
      const float* W; int8_t* wk; int idx, K, H;
      if (id < 131072)       { idx = id;          W = W1; wk = wk1; K = 256; H = 512; }
      else if (id < 393216)  { idx = id - 131072; W = W2; wk = wk2; K = 512; H = 512; }
      else if (id < 655360)  { idx = id - 393216; W = W3; wk = wk3; K = 512; H = 512; }
      else                   { idx = id - 655360; W = W4; wk = wk4; K = 512; H = 35;  }
      int h = idx / K;
      int k = idx - h * K;
      int8_t bits = 0;
      if (h < H) {
        float w  = W[h * K + k];
        float wc = fminf(1.0f, fmaxf(0.001f, w));
        float v  = (wc - 0.001f) / SCALE_F;
        float q  = rintf(v);               // round-half-even, matches np.round; 0..31
        bits = (int8_t)q;
      }
      wk[idx] = bits;
    }
  }
  grid.sync();
  // ---------------- P1: gemm1 (K=256)
  gemm_tiles(chs, wk1, mbuf, 256, 512, 4, 1000, As, Bs);
  grid.sync();
  // ---------------- P2: scan1
  if (gwave < 512)
    scan_col<512, 512, true, false, true>(gwave >> 3, (gwave & 7) * 64 + lane, lane0,
                                          mbuf, n_ch, b1, spk1, sbuf, n1, nullptr);
  grid.sync();
  // ---------------- P3: gemm2
  gemm_tiles(sbuf, wk2, mbuf, 512, 512, 4, 1000, As, Bs);
  grid.sync();
  // ---------------- P4: scan2
  if (gwave < 512)
    scan_col<512, 512, true, false, true>(gwave >> 3, (gwave & 7) * 64 + lane, lane0,
                                          mbuf, n1, b2, spk2, sbuf, n2, nullptr);
  grid.sync();
  // ---------------- P5: gemm3
  gemm_tiles(sbuf, wk3, mbuf, 512, 512, 4, 1000, As, Bs);
  grid.sync();
  // ---------------- P6: scan3
  if (gwave < 512)
    scan_col<512, 512, true, false, true>(gwave >> 3, (gwave & 7) * 64 + lane, lane0,
                                          mbuf, n2, b3, spk3, sbuf, n3, nullptr);
  grid.sync();
  // ---------------- P7: gemm4 (naive per-wave 64x64 tiles, 500 waves)
  if (gwave < 500) gemm64(sbuf, wk4, mbuf, gwave * 64, lane);
  grid.sync();
  // ---------------- P8: scan4
  if (gwave < 35) {
    int colid = gwave * 64 + lane;       // < 2240 = 64*35
    scan_col<35, 64, false, true, false>(colid / 35, colid % 35, lane0,
                                         mbuf, n3, b4, spk4, nullptr, nullptr, mem4);
  }
}

// ================================================================ legacy kernels (fallback path)
__global__ __launch_bounds__(256) void k_prep_cochlea(const float* __restrict__ W1,
                                                      const float* __restrict__ W2,
                                                      const float* __restrict__ W3,
                                                      const float* __restrict__ W4,
                                                      int8_t* __restrict__ wk1,
                                                      int8_t* __restrict__ wk2,
                                                      int8_t* __restrict__ wk3,
                                                      int8_t* __restrict__ wk4,
                                                      const float* __restrict__ x,
                                                      const float* __restrict__ Wch,
                                                      const float* __restrict__ cbetas,
                                                      int8_t* __restrict__ chs,
                                                      int* __restrict__ n_ch) {
  __shared__ float xs[TT];
  if (blockIdx.x < 2688) {
    int id = blockIdx.x * 256 + threadIdx.x;
    const float* W; int8_t* wk; int idx, K, H;
    if (id < 131072)       { idx = id;          W = W1; wk = wk1; K = 256; H = 512; }
    else if (id < 393216)  { idx = id - 131072; W = W2; wk = wk2; K = 512; H = 512; }
    else if (id < 655360)  { idx = id - 393216; W = W3; wk = wk3; K = 512; H = 512; }
    else                   { idx = id - 655360; W = W4; wk = wk4; K = 512; H = 35;  }
    int h = idx / K;
    int k = idx - h * K;
    int8_t bits = 0;
    if (h < H) {
      float w  = W[h * K + k];
      float wc = fminf(1.0f, fmaxf(0.001f, w));
      float v  = (wc - 0.001f) / SCALE_F;
      float q  = rintf(v);
      bits = (int8_t)q;
    }
    wk[idx] = bits;
  } else {
    int b = blockIdx.x - 2688;
    int i = threadIdx.x;
    for (int t = threadIdx.x; t < TT; t += 256) xs[t] = x[b * TT + t];
    __syncthreads();
    float w    = Wch[i];
    float beta = fminf(1.0f, fmaxf(0.0f, cbetas[i]));
    float mem  = 0.0f;
    for (int t = 0; t < TT; ++t) {
      float cur = __fmul_rn(xs[t], w);
      int   rs  = (mem > 1.0f);
      float t2  = __fadd_rn(__fmul_rn(beta, mem), cur);
      mem = rs ? __fsub_rn(t2, 1.0f) : t2;
      int spk = (mem > 1.0f);
      int row = t * BB + b;
      chs[(size_t)row * IND + i] = (int8_t)spk;
      unsigned long long bal = __ballot(spk);
      if ((threadIdx.x & 63) == 0) atomicAdd(n_ch + row, (int)__popcll(bal));
    }
  }
}

template<int KB>
__global__ __launch_bounds__(256) void k_gemm_lds(const int8_t* __restrict__ A,
                                                  const int8_t* __restrict__ B,
                                                  uint16_t* __restrict__ M,
                                                  int Hp, int coltiles) {
  __shared__ __align__(16) int8_t As[128 * 128];
  __shared__ __align__(16) int8_t Bs[128 * 128];
  gemm_tiles(A, B, M, KB, Hp, coltiles, gridDim.x, As, Bs);
}

template<int KB>
__global__ __launch_bounds__(256) void k_gemm_naive(const int8_t* __restrict__ A,
                                                    const int8_t* __restrict__ B,
                                                    uint16_t* __restrict__ M,
                                                    int Hp, int coltiles) {
  int wid  = (blockIdx.x * 256 + threadIdx.x) >> 6;
  int lane = threadIdx.x & 63;
  gemm64(A, B, M, wid * 64, lane);
}

template<int H, int Hp, bool WS, bool WM, bool WN, bool UB>
__global__ __launch_bounds__(64) void k_scan(const uint16_t* __restrict__ M,
                                             const int* __restrict__ nrow,
                                             const float* __restrict__ pbeta,
                                             float* __restrict__ spk_out,
                                             int8_t* __restrict__ s_out,
                                             int* __restrict__ n_out,
                                             float* __restrict__ mem_out) {
  int b, h;
  if constexpr (UB) {
    constexpr int BPB = H / 64;
    b = blockIdx.x / BPB;
    h = (blockIdx.x % BPB) * 64 + threadIdx.x;
  } else {
    int t = blockIdx.x * 64 + threadIdx.x;
    if (t >= BB * H) return;
    b = t / H; h = t - b * H;
  }
  scan_col<H, Hp, WS, WM, WN>(b, h, threadIdx.x == 0, M, nrow, pbeta,
                              spk_out, s_out, n_out, mem_out);
}

// ================================================================ launch
extern "C" void kernel_launch(void* const* d_in, const int* in_sizes, int n_in,
                              void* d_out, int out_size, void* d_ws, size_t ws_size,
                              hipStream_t stream) {
  const float* x      = (const float*)d_in[0];
  const float* Wch    = (const float*)d_in[1];
  const float* W1     = (const float*)d_in[2];
  const float* W2     = (const float*)d_in[3];
  const float* W3     = (const float*)d_in[4];
  const float* W4     = (const float*)d_in[5];
  const float* cbetas = (const float*)d_in[6];
  const float* b1     = (const float*)d_in[7];
  const float* b2     = (const float*)d_in[8];
  const float* b3     = (const float*)d_in[9];
  const float* b4     = (const float*)d_in[10];

  uint8_t* ws = (uint8_t*)d_ws;
  int8_t*   wk1  = (int8_t*)(ws + 0);          // 512*256   = 131072
  int8_t*   wk2  = (int8_t*)(ws + 131072);     // 512*512   = 262144
  int8_t*   wk3  = (int8_t*)(ws + 393216);     // 262144
  int8_t*   wk4  = (int8_t*)(ws + 655360);     // 64*512    = 32768
  int*      n_ch = (int*)(ws + 688128);        // 32000*4 each
  int*      n1   = (int*)(ws + 816128);
  int*      n2   = (int*)(ws + 944128);
  int*      n3   = (int*)(ws + 1072128);       // ends 1200128
  int8_t*   chs  = (int8_t*)(ws + 1200128);    // 32000*256 = 8192000
  int8_t*   sbuf = (int8_t*)(ws + 9392128);    // 32000*512 = 16384000
  uint16_t* mbuf = (uint16_t*)(ws + 25776128); // 32000*512*2 -> ends 58544128

  float* out  = (float*)d_out;
  float* spk1 = out;                // 500*64*512
  float* spk2 = out + 16384000;
  float* spk3 = out + 32768000;
  float* spk4 = out + 49152000;     // 500*64*35
  float* mem4 = out + 50272000;

  // ---- fused cooperative path (counters zeroed inside the kernel)
  void* args[] = {
    (void*)&x, (void*)&Wch, (void*)&cbetas,
    (void*)&W1, (void*)&W2, (void*)&W3, (void*)&W4,
    (void*)&b1, (void*)&b2, (void*)&b3, (void*)&b4,
    (void*)&wk1, (void*)&wk2, (void*)&wk3, (void*)&wk4,
    (void*)&chs, (void*)&sbuf, (void*)&mbuf,
    (void*)&n_ch, (void*)&n1, (void*)&n2, (void*)&n3,
    (void*)&spk1, (void*)&spk2, (void*)&spk3, (void*)&spk4, (void*)&mem4
  };
  hipError_t e = hipLaunchCooperativeKernel((const void*)k_fused, dim3(1024), dim3(256),
                                            args, 0, stream);
  if (e == hipSuccess) return;
  (void)hipGetLastError();   // clear sticky error, fall back to legacy sequence

  hipMemsetAsync(ws + 688128, 0, 512000, stream);
  k_prep_cochlea<<<2752, 256, 0, stream>>>(W1, W2, W3, W4, wk1, wk2, wk3, wk4,
                                           x, Wch, cbetas, chs, n_ch);
  k_gemm_lds<256><<<1000, 256, 0, stream>>>(chs, wk1, mbuf, 512, 4);
  k_scan<512, 512, true, false, true, true><<<512, 64, 0, stream>>>(mbuf, n_ch, b1, spk1, sbuf, n1, nullptr);
  k_gemm_lds<512><<<1000, 256, 0, stream>>>(sbuf, wk2, mbuf, 512, 4);
  k_scan<512, 512, true, false, true, true><<<512, 64, 0, stream>>>(mbuf, n1, b2, spk2, sbuf, n2, nullptr);
  k_gemm_lds<512><<<1000, 256, 0, stream>>>(sbuf, wk3, mbuf, 512, 4);
  k_scan<512, 512, true, false, true, true><<<512, 64, 0, stream>>>(mbuf, n2, b3, spk3, sbuf, n3, nullptr);
  k_gemm_naive<512><<<125, 256, 0, stream>>>(sbuf, wk4, mbuf, 64, 1);
  k_scan<35, 64, false, true, false, false><<<35, 64, 0, stream>>>(mbuf, n3, b4, spk4, nullptr, nullptr, mem4);
}

// Round 6
// 1430.565 us; speedup vs baseline: 1.0620x; 1.0620x over previous
//
#include <hip/hip_runtime.h>
#include <stdint.h>

#define TT   500
#define BB   64
#define IND  256
#define HD   512
#define OD   35
#define ROWS (TT*BB)   // 32000

typedef __attribute__((ext_vector_type(4))) int   i32x4;
typedef __attribute__((ext_vector_type(4))) float f32x4;

// fp32 scale exactly as numpy computes it
#define SCALE_F ((float)((1.0 - 0.001) / 31.0))

#define AGT __HIP_MEMORY_SCOPE_AGENT

__device__ __forceinline__ uint32_t ald32(const void* p) {
  return __hip_atomic_load((uint32_t*)p, __ATOMIC_RELAXED, AGT);
}
__device__ __forceinline__ uint64_t ald64(const void* p) {
  return __hip_atomic_load((uint64_t*)p, __ATOMIC_RELAXED, AGT);
}
__device__ __forceinline__ void ast32(void* p, uint32_t v) {
  __hip_atomic_store((uint32_t*)p, v, __ATOMIC_RELAXED, AGT);
}
__device__ __forceinline__ void aadd(int* p, int v) {
  (void)__hip_atomic_fetch_add(p, v, __ATOMIC_RELAXED, AGT);
}
__device__ __forceinline__ int apoll(const int* p) {
  return __hip_atomic_load((int*)p, __ATOMIC_RELAXED, AGT);
}
__device__ __forceinline__ int tget(int* p) {
  return __hip_atomic_fetch_add(p, 1, __ATOMIC_RELAXED, AGT);
}
// per-wave: all prior VMEM (incl. write-through stores) complete
__device__ __forceinline__ void drain() {
  asm volatile("" ::: "memory");
  __builtin_amdgcn_s_waitcnt(0);
  asm volatile("" ::: "memory");
}
// acquire: invalidate local L2 so subsequent PLAIN loads (incl. global_load_lds)
// see fresh data written by other XCDs
__device__ __forceinline__ void acq_fence() {
  __builtin_amdgcn_fence(__ATOMIC_ACQUIRE, "agent");
}
__device__ __forceinline__ void waitflag(const int* f, int want) {
  while (apoll(f) < want) __builtin_amdgcn_s_sleep(8);
  asm volatile("" ::: "memory");
}

__device__ __forceinline__ void load16_lds(const int8_t* g, int8_t* l) {
  __builtin_amdgcn_global_load_lds((const __attribute__((address_space(1))) void*)g,
                                   (__attribute__((address_space(3))) void*)l, 16, 0, 0);
}

// ---------------- flag-area layout (int indices into F) ----------------
#define T_G1 0
#define T_S1 1
#define T_G2 2
#define T_S2 3
#define T_G3 4
#define T_S3 5
#define T_G4 6
#define T_S4 7
#define FI_PREP 16        // ready: 1792 (448 blocks x 4 waves)
#define FI_CD   32        // cdone[50], ready 256 (64 blocks x 4 waves)
#define FI_G1   96        // g1done[250], ready 16 (4 coltiles x 4 waves)
#define FI_S1   352       // s1done[10], ready 128 (128 wave-jobs)
#define FI_G2   384
#define FI_S2   640
#define FI_G3   672
#define FI_S3   928
#define FI_G4   960       // g4done[50], ready 10 (10 per-t wave jobs)

struct SParams {
  const float *x, *Wch, *cbetas, *W1, *W2, *W3, *W4, *b1, *b2, *b3, *b4;
  uint32_t *wk1, *wk2, *wk3, *wk4;     // int8 data, stored packed as u32
  int8_t *chs, *sbufA, *sbufB;
  uint16_t *mbuf, *mbuf4;
  int *nch, *n1, *n2, *n3;
  int *F;
  float *spk1, *spk2, *spk3, *spk4, *mem4;
};

// ================================================================ fused pieces

// one 128x128 tile, i8 MFMA, verified staging/swizzle; write-through M stores;
// waits an input flag (+acquire fence: staging uses plain global_load_lds),
// signals an output flag (per wave).
template<int KB>
__device__ __forceinline__ void gemm_tile_f(const int8_t* A, const int8_t* B,
                                            uint16_t* M, int Hp, int rt, int ct,
                                            int8_t* As, int8_t* Bs,
                                            int* FL, int inbase, int indiv, int inwant,
                                            int outbase) {
  int tid = threadIdx.x, lane = tid & 63, w = tid >> 6;
  waitflag(FL + inbase + (2 * rt + 1) / indiv, inwant);
  acq_fence();
  int r0 = rt * 128, c0 = ct * 128;
  int wr = (w >> 1) * 64, wc = (w & 1) * 64;
  int lr = lane & 15, kgf = lane >> 4;
  i32x4 acc[4][4];
#pragma unroll
  for (int i = 0; i < 4; ++i)
#pragma unroll
    for (int j = 0; j < 4; ++j) acc[i][j] = (i32x4){0, 0, 0, 0};
  for (int k0 = 0; k0 < KB; k0 += 128) {
    __syncthreads();
#pragma unroll
    for (int i2 = 0; i2 < 4; ++i2) {
      int L = i2 * 256 + tid; int row = L >> 3, c = L & 7; int kg = c ^ (row & 7);
      load16_lds(A + (size_t)(r0 + row) * KB + k0 + kg * 16, &As[(i2 * 256 + w * 64) * 16]);
    }
#pragma unroll
    for (int i2 = 0; i2 < 4; ++i2) {
      int L = i2 * 256 + tid; int row = L >> 3, c = L & 7; int kg = c ^ (row & 7);
      load16_lds(B + (size_t)(c0 + row) * KB + k0 + kg * 16, &Bs[(i2 * 256 + w * 64) * 16]);
    }
    __syncthreads();
#pragma unroll
    for (int kk = 0; kk < 2; ++kk) {
      i32x4 a[4], bb[4];
#pragma unroll
      for (int s = 0; s < 4; ++s) {
        int arow = wr + s * 16 + lr; int sa = (kk * 4 + kgf) ^ (arow & 7);
        a[s] = *(const i32x4*)&As[arow * 128 + sa * 16];
        int brow = wc + s * 16 + lr; int sb2 = (kk * 4 + kgf) ^ (brow & 7);
        bb[s] = *(const i32x4*)&Bs[brow * 128 + sb2 * 16];
      }
#pragma unroll
      for (int ar = 0; ar < 4; ++ar)
#pragma unroll
        for (int cs = 0; cs < 4; ++cs)
          acc[ar][cs] = __builtin_amdgcn_mfma_i32_16x16x64_i8(a[ar], bb[cs], acc[ar][cs], 0, 0, 0);
    }
  }
  // paired write-through stores: even lane stores (col, col+1)
  int oc = lane & 15, rb = (lane >> 4) * 4;
#pragma unroll
  for (int ar = 0; ar < 4; ++ar)
#pragma unroll
    for (int i = 0; i < 4; ++i) {
      size_t rowoff = (size_t)(r0 + wr + ar * 16 + rb + i) * Hp;
#pragma unroll
      for (int cs = 0; cs < 4; ++cs) {
        int v = acc[ar][cs][i];
        int pv = __shfl_down(v, 1);
        if (!(lane & 1))
          ast32(&M[rowoff + c0 + wc + cs * 16 + oc],
                ((uint32_t)(uint16_t)v) | (((uint32_t)(uint16_t)pv) << 16));
      }
    }
  drain();
  if (lane == 0) aadd(FL + outbase + rt, 1);
}

// layer-4 per-wave 64x64 tile (t = wave's timestep); A read via sc loads (sbufA reused)
__device__ __forceinline__ void gemm64_f(int t, const int8_t* A, const int8_t* B,
                                         uint16_t* M, int* FL) {
  int lane = threadIdx.x & 63;
  waitflag(FL + FI_S3 + t / 50, 128);
  acq_fence();
  const int KB = 512, Hp = 64;
  int r0 = t * 64;
  int lr = lane & 15, lk = (lane >> 4) * 16;
  const int8_t* ap = A + (size_t)(r0 + lr) * KB + lk;
  const int8_t* bp = B + (size_t)lr * KB + lk;
  i32x4 acc[4][4];
#pragma unroll
  for (int i = 0; i < 4; ++i)
#pragma unroll
    for (int j = 0; j < 4; ++j) acc[i][j] = (i32x4){0, 0, 0, 0};
#pragma unroll 2
  for (int k = 0; k < KB / 64; ++k) {
    i32x4 a[4], bb[4];
#pragma unroll
    for (int s = 0; s < 4; ++s) {
      const uint64_t* pa = (const uint64_t*)(ap + (size_t)s * 16 * KB + k * 64);
      uint64_t lo = ald64(pa), hi = ald64(pa + 1);
      a[s] = (i32x4){(int)(uint32_t)lo, (int)(uint32_t)(lo >> 32),
                     (int)(uint32_t)hi, (int)(uint32_t)(hi >> 32)};
      bb[s] = *(const i32x4*)(bp + (size_t)s * 16 * KB + k * 64);   // wk4 immutable post-gate
    }
#pragma unroll
    for (int ar = 0; ar < 4; ++ar)
#pragma unroll
      for (int cs = 0; cs < 4; ++cs)
        acc[ar][cs] = __builtin_amdgcn_mfma_i32_16x16x64_i8(a[ar], bb[cs], acc[ar][cs], 0, 0, 0);
  }
  int oc = lane & 15, rb = (lane >> 4) * 4;
#pragma unroll
  for (int ar = 0; ar < 4; ++ar)
#pragma unroll
    for (int i = 0; i < 4; ++i) {
      size_t rowoff = (size_t)(r0 + ar * 16 + rb + i) * Hp;
#pragma unroll
      for (int cs = 0; cs < 4; ++cs) {
        int v = acc[ar][cs][i];
        int pv = __shfl_down(v, 1);
        if (!(lane & 1))
          ast32(&M[rowoff + cs * 16 + oc],
                ((uint32_t)(uint16_t)v) | (((uint32_t)(uint16_t)pv) << 16));
      }
    }
  drain();
  if (lane == 0) aadd(FL + FI_G4 + t / 10, 1);
}

// LIF scan wave-job, 4 columns/thread. np-exact fp32 recurrence (identical ops).
// 3-deep pipeline; per-10t flag waits (5 rowtiles polled by lanes 0..4);
// sc loads for M/n (bypass stale L2, no fence -> pipeline preserved);
// NT float4 spk; write-through packed sbuf; per-50t signal.
// M element stride per t = 64 rows * 512 = 32768 u16 = 8192 u64.  [FIXED r6]
__device__ __forceinline__ void scan512_f(int j, const uint16_t* M, const int* nprev,
                                          const float* pbeta, float* spk, int8_t* sb,
                                          int* nout, int* FL, int inbase, int outbase) {
  int lane = threadIdx.x & 63;
  int b = j >> 1, h0 = (j & 1) * 256 + lane * 4;
  float beta = fminf(1.0f, fmaxf(0.0f, *pbeta));
  const double DSCALE = (double)SCALE_F;
  const double DWMIN  = (double)0.001f;
  float mm[4] = {0.f, 0.f, 0.f, 0.f};
  const uint64_t* Mp = (const uint64_t*)(M + (size_t)b * 512 + h0);
  const int* np = nprev + b;                                        // stride 64 ints / t
  uint64_t mA[10], mB[10], mC[10]; uint32_t nA[10], nB[10], nC[10];

#define SWAITG(G)                                                              \
  { int rr = 5 * (G);                                                          \
    int fv = (lane < 5) ? apoll(FL + inbase + rr + lane) : 16;                 \
    while (__ballot(fv < 16)) {                                                \
      __builtin_amdgcn_s_sleep(4);                                             \
      fv = (lane < 5) ? apoll(FL + inbase + rr + lane) : 16;                   \
    }                                                                          \
    asm volatile("" ::: "memory"); }

#define SLOADG(mv, nv, G)                                                      \
  { int T0 = (G) * 10;                                                         \
    _Pragma("unroll") for (int q = 0; q < 10; ++q) {                           \
      mv[q] = ald64(Mp + (size_t)(T0 + q) * 8192);                             \
      nv[q] = ald32(np + (T0 + q) * 64); } }

#define SSTEPG(mv, nv, G)                                                      \
  { int T0 = (G) * 10;                                                         \
    _Pragma("unroll") for (int q = 0; q < 10; ++q) {                           \
      int t = T0 + q; int row = t * 64 + b;                                    \
      uint64_t mw = mv[q];                                                     \
      double nterm = (double)(int)nv[q] * DWMIN;                               \
      uint32_t sp = 0; int cnt = 0; f32x4 sf;                                  \
      _Pragma("unroll") for (int c = 0; c < 4; ++c) {                          \
        float cur = (float)((double)(int)((mw >> (16 * c)) & 0xffff) * DSCALE + nterm); \
        int rs = (mm[c] > 1.0f);                                               \
        float t2 = __fadd_rn(__fmul_rn(beta, mm[c]), cur);                     \
        mm[c] = rs ? __fsub_rn(t2, 1.0f) : t2;                                 \
        int s = (mm[c] > 1.0f);                                                \
        sp |= ((uint32_t)s) << (8 * c); cnt += s; sf[c] = s ? 1.0f : 0.0f; }   \
      __builtin_nontemporal_store(sf, (f32x4*)(spk + (size_t)t * 32768 + b * 512 + h0)); \
      ast32(sb + (size_t)row * 512 + h0, sp);                                  \
      int tot = cnt;                                                           \
      _Pragma("unroll") for (int d = 1; d < 64; d <<= 1) tot += __shfl_xor(tot, d); \
      if (lane == 0) aadd(nout + row, tot);                                    \
      if ((t % 50) == 49) { drain(); if (lane == 0) aadd(FL + outbase + t / 50, 1); } } }

  SWAITG(0) SLOADG(mA, nA, 0)
  SWAITG(1) SLOADG(mB, nB, 1)
  for (int g = 0; g < 48; g += 3) {
    SWAITG(g + 2) SLOADG(mC, nC, g + 2)
    SSTEPG(mA, nA, g)
    if (g + 3 < 50) { SWAITG(g + 3) SLOADG(mA, nA, g + 3) }
    SSTEPG(mB, nB, g + 1)
    if (g + 4 < 50) { SWAITG(g + 4) SLOADG(mB, nB, g + 4) }
    SSTEPG(mC, nC, g + 2)
  }
  SSTEPG(mA, nA, 48)
  SSTEPG(mB, nB, 49)
#undef SWAITG
#undef SLOADG
#undef SSTEPG
}

// layer-4 scan wave-job: one column per lane.
// M4 element stride per t = 64 rows * 64 = 4096 u16 = 1024 u64.  [FIXED r6]
__device__ __forceinline__ void scan4_f(int j, const uint16_t* M4, const int* n3,
                                        const float* pbeta, float* spk4, float* mem4,
                                        int* FL) {
  int lane = threadIdx.x & 63;
  int colid = j * 64 + lane;            // < 2240 for j < 35
  int b = colid / 35, h = colid - b * 35;
  float beta = fminf(1.0f, fmaxf(0.0f, *pbeta));
  const double DSCALE = (double)SCALE_F;
  const double DWMIN  = (double)0.001f;
  float m = 0.0f;
  const uint64_t* Mp = (const uint64_t*)(M4 + (size_t)b * 64 + (h & ~3));
  int sub = h & 3;
  const int* np = n3 + b;
  uint64_t mA[10], mB[10], mC[10]; uint32_t nA[10], nB[10], nC[10];

#define QWAITG(G)  waitflag(FL + FI_G4 + (G), 10);

#define QLOADG(mv, nv, G)                                                      \
  { int T0 = (G) * 10;                                                         \
    _Pragma("unroll") for (int q = 0; q < 10; ++q) {                           \
      mv[q] = ald64(Mp + (size_t)(T0 + q) * 1024);                             \
      nv[q] = ald32(np + (T0 + q) * 64); } }

#define QSTEPG(mv, nv, G)                                                      \
  { int T0 = (G) * 10;                                                         \
    _Pragma("unroll") for (int q = 0; q < 10; ++q) {                           \
      int t = T0 + q;                                                          \
      float cur = (float)((double)(int)((mv[q] >> (16 * sub)) & 0xffff) * DSCALE \
                          + (double)(int)nv[q] * DWMIN);                       \
      int rs = (m > 1.0f);                                                     \
      float t2 = __fadd_rn(__fmul_rn(beta, m), cur);                           \
      m = rs ? __fsub_rn(t2, 1.0f) : t2;                                       \
      int s = (m > 1.0f);                                                      \
      __builtin_nontemporal_store(s ? 1.0f : 0.0f, &spk4[(size_t)t * 2240 + colid]); \
      __builtin_nontemporal_store(m, &mem4[(size_t)t * 2240 + colid]); } }

  QWAITG(0) QLOADG(mA, nA, 0)
  QWAITG(1) QLOADG(mB, nB, 1)
  for (int g = 0; g < 48; g += 3) {
    QWAITG(g + 2) QLOADG(mC, nC, g + 2)
    QSTEPG(mA, nA, g)
    if (g + 3 < 50) { QWAITG(g + 3) QLOADG(mA, nA, g + 3) }
    QSTEPG(mB, nB, g + 1)
    if (g + 4 < 50) { QWAITG(g + 4) QLOADG(mB, nB, g + 4) }
    QSTEPG(mC, nC, g + 2)
  }
  QSTEPG(mA, nA, 48)
  QSTEPG(mB, nB, 49)
#undef QWAITG
#undef QLOADG
#undef QSTEPG
}

// ================================================================ streaming kernel
__global__ __launch_bounds__(256, 2) void k_stream(SParams P) {
  __shared__ __align__(16) int8_t As[16384];
  __shared__ __align__(16) int8_t Bs[16384];
  __shared__ int s_tk;
  int tid = threadIdx.x, lane = tid & 63, w = tid >> 6, blk = blockIdx.x;

  // ---------------- P0: cochlea (blocks 0..63) || weight prep (blocks 64..511)
  if (blk < 64) {
    float* xs = (float*)As;
    int b = blk;
    for (int t = tid; t < TT; t += 256) xs[t] = P.x[b * TT + t];
    __syncthreads();
    int i = tid;
    float wv = P.Wch[i];
    float beta = fminf(1.0f, fmaxf(0.0f, P.cbetas[i]));
    float mem = 0.0f;
    for (int t = 0; t < TT; ++t) {
      float cur = __fmul_rn(xs[t], wv);
      int rs = (mem > 1.0f);
      float t2 = __fadd_rn(__fmul_rn(beta, mem), cur);
      mem = rs ? __fsub_rn(t2, 1.0f) : t2;
      int spk = (mem > 1.0f);
      int row = t * BB + b;
      int s1 = __shfl_down(spk, 1), s2 = __shfl_down(spk, 2), s3 = __shfl_down(spk, 3);
      if ((lane & 3) == 0)
        ast32(P.chs + (size_t)row * IND + i,
              (uint32_t)spk | ((uint32_t)s1 << 8) | ((uint32_t)s2 << 16) | ((uint32_t)s3 << 24));
      unsigned long long bal = __ballot(spk);
      if (lane == 0) aadd(P.nch + row, (int)__popcll(bal));
      if ((t % 10) == 9) { drain(); if (lane == 0) aadd(P.F + FI_CD + t / 10, 1); }
    }
  } else {
    int gid = (blk - 64) * 256 + tid;
    const int stride = 448 * 256;                 // 114688
    for (int wi = gid; wi < 172032; wi += stride) {  // 688128 int8 elems / 4
      int e0 = wi * 4;
      const float* W; uint32_t* wk; int K, H, base;
      if (e0 < 131072)      { base = 0;      W = P.W1; wk = P.wk1; K = 256; H = 512; }
      else if (e0 < 393216) { base = 131072; W = P.W2; wk = P.wk2; K = 512; H = 512; }
      else if (e0 < 655360) { base = 393216; W = P.W3; wk = P.wk3; K = 512; H = 512; }
      else                  { base = 655360; W = P.W4; wk = P.wk4; K = 512; H = 35;  }
      int idx0 = e0 - base;
      int h = idx0 / K, k0 = idx0 - h * K;
      uint32_t pack = 0;
      if (h < H) {
#pragma unroll
        for (int c = 0; c < 4; ++c) {
          float wv = W[h * K + k0 + c];
          float wc = fminf(1.0f, fmaxf(0.001f, wv));
          float v = (wc - 0.001f) / SCALE_F;
          float q = rintf(v);
          pack |= ((uint32_t)(uint8_t)(int)q) << (8 * c);
        }
      }
      ast32(wk + (idx0 >> 2), pack);
    }
    drain();
    if (lane == 0) aadd(P.F + FI_PREP, 1);        // ready: 448*4 = 1792
  }
  // weights ready gate; acquire so plain wk reads below see fresh data
  waitflag(P.F + FI_PREP, 1792);
  acq_fence();

#define PHASE(PH, NJ, BODY)                                                    \
  for (;;) {                                                                   \
    __syncthreads();                                                           \
    if (tid == 0) s_tk = tget(P.F + (PH));                                     \
    __syncthreads();                                                           \
    int tk = s_tk;                                                             \
    if (tk >= (NJ)) break;                                                     \
    BODY;                                                                      \
  }

  PHASE(T_G1, 1000, (gemm_tile_f<256>(P.chs, (const int8_t*)P.wk1, P.mbuf, 512,
                                      tk >> 2, tk & 3, As, Bs, P.F, FI_CD, 10, 256, FI_G1)))
  PHASE(T_S1, 32,   (scan512_f(tk * 4 + w, P.mbuf, P.nch, P.b1, P.spk1, P.sbufA, P.n1,
                               P.F, FI_G1, FI_S1)))
  PHASE(T_G2, 1000, (gemm_tile_f<512>(P.sbufA, (const int8_t*)P.wk2, P.mbuf, 512,
                                      tk >> 2, tk & 3, As, Bs, P.F, FI_S1, 50, 128, FI_G2)))
  PHASE(T_S2, 32,   (scan512_f(tk * 4 + w, P.mbuf, P.n1, P.b2, P.spk2, P.sbufB, P.n2,
                               P.F, FI_G2, FI_S2)))
  PHASE(T_G3, 1000, (gemm_tile_f<512>(P.sbufB, (const int8_t*)P.wk3, P.mbuf, 512,
                                      tk >> 2, tk & 3, As, Bs, P.F, FI_S2, 50, 128, FI_G3)))
  PHASE(T_S3, 32,   (scan512_f(tk * 4 + w, P.mbuf, P.n2, P.b3, P.spk3, P.sbufA, P.n3,
                               P.F, FI_G3, FI_S3)))
  PHASE(T_G4, 125,  (gemm64_f(tk * 4 + w, P.sbufA, (const int8_t*)P.wk4, P.mbuf4, P.F)))
  PHASE(T_S4, 9,    ({ int j4 = tk * 4 + w;
                       if (j4 < 35) scan4_f(j4, P.mbuf4, P.n3, P.b4, P.spk4, P.mem4, P.F); }))
#undef PHASE
}

// ================================================================ legacy (round-3 verbatim, 520 us fallback)
__global__ __launch_bounds__(256) void k_prep_cochlea(const float* __restrict__ W1,
                                                      const float* __restrict__ W2,
                                                      const float* __restrict__ W3,
                                                      const float* __restrict__ W4,
                                                      int8_t* __restrict__ wk1,
                                                      int8_t* __restrict__ wk2,
                                                      int8_t* __restrict__ wk3,
                                                      int8_t* __restrict__ wk4,
                                                      const float* __restrict__ x,
                                                      const float* __restrict__ Wch,
                                                      const float* __restrict__ cbetas,
                                                      int8_t* __restrict__ chs,
                                                      int* __restrict__ n_ch) {
  __shared__ float xs[TT];
  if (blockIdx.x < 2688) {
    int id = blockIdx.x * 256 + threadIdx.x;
    const float* W; int8_t* wk; int idx, K, H;
    if (id < 131072)       { idx = id;          W = W1; wk = wk1; K = 256; H = 512; }
    else if (id < 393216)  { idx = id - 131072; W = W2; wk = wk2; K = 512; H = 512; }
    else if (id < 655360)  { idx = id - 393216; W = W3; wk = wk3; K = 512; H = 512; }
    else                   { idx = id - 655360; W = W4; wk = wk4; K = 512; H = 35;  }
    int h = idx / K;
    int k = idx - h * K;
    int8_t bits = 0;
    if (h < H) {
      float w = W[h * K + k];
      float wc = fminf(1.0f, fmaxf(0.001f, w));
      float v = (wc - 0.001f) / SCALE_F;
      float q = rintf(v);
      bits = (int8_t)q;
    }
    wk[idx] = bits;
  } else {
    int b = blockIdx.x - 2688;
    int i = threadIdx.x;
    for (int t = threadIdx.x; t < TT; t += 256) xs[t] = x[b * TT + t];
    __syncthreads();
    float w = Wch[i];
    float beta = fminf(1.0f, fmaxf(0.0f, cbetas[i]));
    float mem = 0.0f;
    for (int t = 0; t < TT; ++t) {
      float cur = __fmul_rn(xs[t], w);
      int rs = (mem > 1.0f);
      float t2 = __fadd_rn(__fmul_rn(beta, mem), cur);
      mem = rs ? __fsub_rn(t2, 1.0f) : t2;
      int spk = (mem > 1.0f);
      int row = t * BB + b;
      chs[(size_t)row * IND + i] = (int8_t)spk;
      unsigned long long bal = __ballot(spk);
      if ((threadIdx.x & 63) == 0) atomicAdd(n_ch + row, (int)__popcll(bal));
    }
  }
}

template<int KB>
__global__ __launch_bounds__(256) void k_gemm_lds(const int8_t* __restrict__ A,
                                                  const int8_t* __restrict__ B,
                                                  uint16_t* __restrict__ M,
                                                  int Hp, int coltiles) {
  __shared__ __align__(16) int8_t As[128 * 128];
  __shared__ __align__(16) int8_t Bs[128 * 128];
  int tid = threadIdx.x;
  int lane = tid & 63, w = tid >> 6;
  int nwg = gridDim.x;
  int bid = blockIdx.x;
  if (!(nwg & 7)) bid = (bid & 7) * (nwg >> 3) + (bid >> 3);
  int rt = bid / coltiles, ct = bid - rt * coltiles;
  int r0 = rt * 128, c0 = ct * 128;
  int wr = (w >> 1) * 64, wc = (w & 1) * 64;
  int lr = lane & 15, kgf = lane >> 4;
  i32x4 acc[4][4];
#pragma unroll
  for (int i = 0; i < 4; ++i)
#pragma unroll
    for (int j = 0; j < 4; ++j) acc[i][j] = (i32x4){0, 0, 0, 0};
  for (int k0 = 0; k0 < KB; k0 += 128) {
    __syncthreads();
#pragma unroll
    for (int i = 0; i < 4; ++i) {
      int L = i * 256 + tid;
      int row = L >> 3, c = L & 7;
      int kg = c ^ (row & 7);
      load16_lds(A + (size_t)(r0 + row) * KB + k0 + kg * 16, &As[(i * 256 + w * 64) * 16]);
    }
#pragma unroll
    for (int i = 0; i < 4; ++i) {
      int L = i * 256 + tid;
      int row = L >> 3, c = L & 7;
      int kg = c ^ (row & 7);
      load16_lds(B + (size_t)(c0 + row) * KB + k0 + kg * 16, &Bs[(i * 256 + w * 64) * 16]);
    }
    __syncthreads();
#pragma unroll
    for (int kk = 0; kk < 2; ++kk) {
      i32x4 a[4], b[4];
#pragma unroll
      for (int s = 0; s < 4; ++s) {
        int arow = wr + s * 16 + lr;
        int sa = (kk * 4 + kgf) ^ (arow & 7);
        a[s] = *(const i32x4*)&As[arow * 128 + sa * 16];
        int brow = wc + s * 16 + lr;
        int sb = (kk * 4 + kgf) ^ (brow & 7);
        b[s] = *(const i32x4*)&Bs[brow * 128 + sb * 16];
      }
#pragma unroll
      for (int ar = 0; ar < 4; ++ar)
#pragma unroll
        for (int cs = 0; cs < 4; ++cs)
          acc[ar][cs] = __builtin_amdgcn_mfma_i32_16x16x64_i8(a[ar], b[cs], acc[ar][cs], 0, 0, 0);
    }
  }
  int oc = lane & 15;
  int rb = (lane >> 4) * 4;
#pragma unroll
  for (int ar = 0; ar < 4; ++ar)
#pragma unroll
    for (int i = 0; i < 4; ++i) {
      size_t rowoff = (size_t)(r0 + wr + ar * 16 + rb + i) * Hp;
#pragma unroll
      for (int cs = 0; cs < 4; ++cs)
        __builtin_nontemporal_store((uint16_t)acc[ar][cs][i],
                                    &M[rowoff + c0 + wc + cs * 16 + oc]);
    }
}

template<int KB>
__global__ __launch_bounds__(256) void k_gemm_naive(const int8_t* __restrict__ A,
                                                    const int8_t* __restrict__ B,
                                                    uint16_t* __restrict__ M,
                                                    int Hp, int coltiles) {
  int wid = (blockIdx.x * 256 + threadIdx.x) >> 6;
  int lane = threadIdx.x & 63;
  int rt = wid / coltiles;
  int ct = wid - rt * coltiles;
  int r0 = rt * 64, c0 = ct * 64;
  int lr = lane & 15;
  int lk = (lane >> 4) * 16;
  const int8_t* ap = A + (size_t)(r0 + lr) * KB + lk;
  const int8_t* bp = B + (size_t)(c0 + lr) * KB + lk;
  i32x4 acc[4][4];
#pragma unroll
  for (int i = 0; i < 4; ++i)
#pragma unroll
    for (int j = 0; j < 4; ++j) acc[i][j] = (i32x4){0, 0, 0, 0};
#pragma unroll 2
  for (int k = 0; k < KB / 64; ++k) {
    i32x4 a[4], b[4];
#pragma unroll
    for (int s = 0; s < 4; ++s) {
      a[s] = *(const i32x4*)(ap + (size_t)s * 16 * KB + k * 64);
      b[s] = *(const i32x4*)(bp + (size_t)s * 16 * KB + k * 64);
    }
#pragma unroll
    for (int ar = 0; ar < 4; ++ar)
#pragma unroll
      for (int cs = 0; cs < 4; ++cs)
        acc[ar][cs] = __builtin_amdgcn_mfma_i32_16x16x64_i8(a[ar], b[cs], acc[ar][cs], 0, 0, 0);
  }
  int oc = lane & 15;
  int rb = (lane >> 4) * 4;
#pragma unroll
  for (int ar = 0; ar < 4; ++ar)
#pragma unroll
    for (int i = 0; i < 4; ++i) {
      size_t rowoff = (size_t)(r0 + ar * 16 + rb + i) * Hp;
#pragma unroll
      for (int cs = 0; cs < 4; ++cs)
        M[rowoff + c0 + cs * 16 + oc] = (uint16_t)acc[ar][cs][i];
    }
}

template<int H, int Hp, bool WS, bool WM, bool WN, bool UB>
__global__ __launch_bounds__(64) void k_scan(const uint16_t* __restrict__ M,
                                             const int* __restrict__ nrow,
                                             const float* __restrict__ pbeta,
                                             float* __restrict__ spk_out,
                                             int8_t* __restrict__ s_out,
                                             int* __restrict__ n_out,
                                             float* __restrict__ mem_out) {
  int b, h;
  if constexpr (UB) {
    constexpr int BPB = H / 64;
    b = blockIdx.x / BPB;
    h = (blockIdx.x % BPB) * 64 + threadIdx.x;
  } else {
    int t = blockIdx.x * 64 + threadIdx.x;
    if (t >= BB * H) return;
    b = t / H; h = t - b * H;
  }
  int tid = b * H + h;
  float beta = fminf(1.0f, fmaxf(0.0f, *pbeta));
  const double DSCALE = (double)SCALE_F;
  const double DWMIN  = (double)0.001f;
  float mem = 0.0f;
  const uint16_t* Mp = M + (size_t)b * Hp + h;
  const int* np = nrow + b;
  uint16_t mA[10], mB[10], mC[10]; int nA[10], nB[10], nC[10];

#define LOADBLK(mv, nv, G)                                                   \
  { int T0 = (G) * 10;                                                       \
    _Pragma("unroll") for (int j = 0; j < 10; ++j) {                         \
      mv[j] = __builtin_nontemporal_load(Mp + (size_t)(T0 + j) * (BB * Hp)); \
      nv[j] = np[(T0 + j) * BB]; } }

#define STEPBLK(mv, nv, G)                                                   \
  { int T0 = (G) * 10;                                                       \
    _Pragma("unroll") for (int j = 0; j < 10; ++j) {                         \
      int t = T0 + j; int row = t * BB + b;                                  \
      float cur = (float)((double)mv[j] * DSCALE + (double)nv[j] * DWMIN);   \
      int rs = (mem > 1.0f);                                                 \
      float t2 = __fadd_rn(__fmul_rn(beta, mem), cur);                       \
      mem = rs ? __fsub_rn(t2, 1.0f) : t2;                                   \
      int spk = (mem > 1.0f);                                                \
      __builtin_nontemporal_store(spk ? 1.0f : 0.0f,                         \
                                  &spk_out[(size_t)t * (BB * H) + tid]);     \
      if (WS) s_out[(size_t)row * H + h] = (int8_t)spk;                      \
      if (WN) { unsigned long long bal = __ballot(spk);                      \
                if (threadIdx.x == 0) atomicAdd(n_out + row, (int)__popcll(bal)); } \
      if (WM) __builtin_nontemporal_store(mem,                               \
                                  &mem_out[(size_t)t * (BB * H) + tid]); } }

  LOADBLK(mA, nA, 0)
  LOADBLK(mB, nB, 1)
  for (int g = 0; g < 48; g += 3) {
    LOADBLK(mC, nC, g + 2)
    STEPBLK(mA, nA, g)
    LOADBLK(mA, nA, g + 3)
    STEPBLK(mB, nB, g + 1)
    LOADBLK(mB, nB, g + 4)
    STEPBLK(mC, nC, g + 2)
  }
  STEPBLK(mA, nA, 48)
  STEPBLK(mB, nB, 49)
#undef LOADBLK
#undef STEPBLK
}

// ================================================================ launch
extern "C" void kernel_launch(void* const* d_in, const int* in_sizes, int n_in,
                              void* d_out, int out_size, void* d_ws, size_t ws_size,
                              hipStream_t stream) {
  const float* x      = (const float*)d_in[0];
  const float* Wch    = (const float*)d_in[1];
  const float* W1     = (const float*)d_in[2];
  const float* W2     = (const float*)d_in[3];
  const float* W3     = (const float*)d_in[4];
  const float* W4     = (const float*)d_in[5];
  const float* cbetas = (const float*)d_in[6];
  const float* b1     = (const float*)d_in[7];
  const float* b2     = (const float*)d_in[8];
  const float* b3     = (const float*)d_in[9];
  const float* b4     = (const float*)d_in[10];

  uint8_t* ws = (uint8_t*)d_ws;
  float* out  = (float*)d_out;
  float* spk1 = out;
  float* spk2 = out + 16384000;
  float* spk3 = out + 32768000;
  float* spk4 = out + 49152000;
  float* mem4 = out + 50272000;

  // ---- streaming layout ----
  // 0 wk1(131072) | wk2(262144) | wk3(262144) | wk4(32768) -> 688128
  // n_ch/n1/n2/n3 (4x128000) -> 1200128 | flags 8192 -> 1208320
  // chs 8192000 -> 9400320 | sbufA 16384000 -> 25784320 | sbufB -> 42168320
  // mbuf 32768000 -> 74936320 | mbuf4 4096000 -> 79032320
  if (ws_size >= 79032320) {
    hipMemsetAsync(ws + 688128, 0, 520192, stream);   // n arrays + flags
    SParams P;
    P.x = x; P.Wch = Wch; P.cbetas = cbetas;
    P.W1 = W1; P.W2 = W2; P.W3 = W3; P.W4 = W4;
    P.b1 = b1; P.b2 = b2; P.b3 = b3; P.b4 = b4;
    P.wk1 = (uint32_t*)(ws + 0);
    P.wk2 = (uint32_t*)(ws + 131072);
    P.wk3 = (uint32_t*)(ws + 393216);
    P.wk4 = (uint32_t*)(ws + 655360);
    P.nch = (int*)(ws + 688128);
    P.n1  = (int*)(ws + 816128);
    P.n2  = (int*)(ws + 944128);
    P.n3  = (int*)(ws + 1072128);
    P.F   = (int*)(ws + 1200128);
    P.chs   = (int8_t*)(ws + 1208320);
    P.sbufA = (int8_t*)(ws + 9400320);
    P.sbufB = (int8_t*)(ws + 25784320);
    P.mbuf  = (uint16_t*)(ws + 42168320);
    P.mbuf4 = (uint16_t*)(ws + 74936320);
    P.spk1 = spk1; P.spk2 = spk2; P.spk3 = spk3; P.spk4 = spk4; P.mem4 = mem4;
    void* ka[] = { (void*)&P };
    hipError_t e = hipLaunchCooperativeKernel((const void*)k_stream, dim3(512), dim3(256),
                                              ka, 0, stream);
    if (e == hipSuccess) return;
    (void)hipGetLastError();
  }

  // ---- legacy fallback (round-3 verified, 520 us) ----
  int8_t*   wk1  = (int8_t*)(ws + 0);
  int8_t*   wk2  = (int8_t*)(ws + 131072);
  int8_t*   wk3  = (int8_t*)(ws + 393216);
  int8_t*   wk4  = (int8_t*)(ws + 655360);
  int*      n_ch = (int*)(ws + 688128);
  int*      n1   = (int*)(ws + 816128);
  int*      n2   = (int*)(ws + 944128);
  int*      n3   = (int*)(ws + 1072128);
  int8_t*   chs  = (int8_t*)(ws + 1200128);
  int8_t*   sbuf = (int8_t*)(ws + 9392128);
  uint16_t* mbuf = (uint16_t*)(ws + 25776128);

  hipMemsetAsync(ws + 688128, 0, 512000, stream);
  k_prep_cochlea<<<2752, 256, 0, stream>>>(W1, W2, W3, W4, wk1, wk2, wk3, wk4,
                                           x, Wch, cbetas, chs, n_ch);
  k_gemm_lds<256><<<1000, 256, 0, stream>>>(chs, wk1, mbuf, 512, 4);
  k_scan<512, 512, true, false, true, true><<<512, 64, 0, stream>>>(mbuf, n_ch, b1, spk1, sbuf, n1, nullptr);
  k_gemm_lds<512><<<1000, 256, 0, stream>>>(sbuf, wk2, mbuf, 512, 4);
  k_scan<512, 512, true, false, true, true><<<512, 64, 0, stream>>>(mbuf, n1, b2, spk2, sbuf, n2, nullptr);
  k_gemm_lds<512><<<1000, 256, 0, stream>>>(sbuf, wk3, mbuf, 512, 4);
  k_scan<512, 512, true, false, true, true><<<512, 64, 0, stream>>>(mbuf, n2, b3, spk3, sbuf, n3, nullptr);
  k_gemm_naive<512><<<125, 256, 0, stream>>>(sbuf, wk4, mbuf, 64, 1);
  k_scan<35, 64, false, true, false, false><<<35, 64, 0, stream>>>(mbuf, n3, b4, spk4, nullptr, nullptr, mem4);
}

// Round 7
// 553.371 us; speedup vs baseline: 2.7455x; 2.5852x over previous
//
#include <hip/hip_runtime.h>
#include <stdint.h>

#define TT   500
#define BB   64
#define IND  256
#define HD   512
#define OD   35

typedef __attribute__((ext_vector_type(4))) int i32x4;

// fp32 scale exactly as numpy computes it
#define SCALE_F ((float)((1.0 - 0.001) / 31.0))

__device__ __forceinline__ void load16_lds(const int8_t* g, int8_t* l) {
  __builtin_amdgcn_global_load_lds((const __attribute__((address_space(1))) void*)g,
                                   (__attribute__((address_space(3))) void*)l, 16, 0, 0);
}

// ---------------------------------------------------------------- prep + cochlea (r3 verbatim)
__global__ __launch_bounds__(256) void k_prep_cochlea(const float* __restrict__ W1,
                                                      const float* __restrict__ W2,
                                                      const float* __restrict__ W3,
                                                      const float* __restrict__ W4,
                                                      int8_t* __restrict__ wk1,
                                                      int8_t* __restrict__ wk2,
                                                      int8_t* __restrict__ wk3,
                                                      int8_t* __restrict__ wk4,
                                                      const float* __restrict__ x,
                                                      const float* __restrict__ Wch,
                                                      const float* __restrict__ cbetas,
                                                      int8_t* __restrict__ chs,
                                                      int* __restrict__ n_ch) {
  __shared__ float xs[TT];
  if (blockIdx.x < 2688) {
    int id = blockIdx.x * 256 + threadIdx.x;
    const float* W; int8_t* wk; int idx, K, H;
    if (id < 131072)       { idx = id;          W = W1; wk = wk1; K = 256; H = 512; }
    else if (id < 393216)  { idx = id - 131072; W = W2; wk = wk2; K = 512; H = 512; }
    else if (id < 655360)  { idx = id - 393216; W = W3; wk = wk3; K = 512; H = 512; }
    else                   { idx = id - 655360; W = W4; wk = wk4; K = 512; H = 35;  }
    int h = idx / K;
    int k = idx - h * K;
    int8_t bits = 0;
    if (h < H) {
      float w  = W[h * K + k];
      float wc = fminf(1.0f, fmaxf(0.001f, w));
      float v  = (wc - 0.001f) / SCALE_F;
      float q  = rintf(v);                 // round-half-even, matches np.round; 0..31
      bits = (int8_t)q;
    }
    wk[idx] = bits;
  } else {
    int b = blockIdx.x - 2688;
    int i = threadIdx.x;
    for (int t = threadIdx.x; t < TT; t += 256) xs[t] = x[b * TT + t];
    __syncthreads();
    float w    = Wch[i];
    float beta = fminf(1.0f, fmaxf(0.0f, cbetas[i]));
    float mem  = 0.0f;
    for (int t = 0; t < TT; ++t) {
      float cur = __fmul_rn(xs[t], w);
      int   rs  = (mem > 1.0f);
      float t2  = __fadd_rn(__fmul_rn(beta, mem), cur);
      mem = rs ? __fsub_rn(t2, 1.0f) : t2;
      int spk = (mem > 1.0f);
      int row = t * BB + b;
      chs[(size_t)row * IND + i] = (int8_t)spk;
      unsigned long long bal = __ballot(spk);
      if ((threadIdx.x & 63) == 0) atomicAdd(n_ch + row, (int)__popcll(bal));
    }
  }
}

// ---------------------------------------------------------------- fused layer: GEMM + LIF scan
// One block = (batch element b) x (64-col slice h0). Block decode b=blk&63 so the
// 8 slice-blocks sharing b land on one XCD (blk%8 == b%8) -> A rows L2-resident.
// Per t-batch of 64: 4-wave i8 MFMA from swizzled LDS -> pm[64][68] u16 in LDS ->
// barrier -> all waves async-issue next A-batch stage (latency hides under scan)
// -> wave0 runs the np-exact serial LIF over the 64 t's. M never touches HBM.
// Slot math: arow&7 == brow&7 == lr&7 (w*16, cs*16 are multiples of 8) -> one slot.
template<int K, bool LAST>
__global__ __launch_bounds__(256) void k_layer(const int8_t* __restrict__ A,
                                               const int8_t* __restrict__ Bw,
                                               const int* __restrict__ nprev,
                                               const float* __restrict__ pbeta,
                                               float* __restrict__ spk_out,
                                               int8_t* __restrict__ s_out,
                                               int* __restrict__ n_out,
                                               float* __restrict__ mem_out) {
  constexpr int CH = K / 16;                 // 16-B chunks per row (32 or 16)
  __shared__ __align__(16) int8_t Bs[64 * K];
  __shared__ __align__(16) int8_t As[64 * K];
  __shared__ uint16_t pm[64][68];            // +4 pad: conflict-free write/read
  __shared__ int nbuf[64];
  __shared__ float sbeta;
  int tid = threadIdx.x, lane = tid & 63, w = tid >> 6;
  int b, h0;
  if (LAST) { b = blockIdx.x;      h0 = 0; }
  else      { b = blockIdx.x & 63; h0 = (blockIdx.x >> 6) * 64; }
  if (tid == 0) sbeta = fminf(1.0f, fmaxf(0.0f, *pbeta));
  // stage B slice [64][K], XOR-swizzled (slot sl holds chunk (sl&~7)|((sl&7)^(row&7)))
#pragma unroll
  for (int i = 0; i < CH / 4; ++i) {
    int L = i * 256 + tid;
    int row = L / CH, sl = L % CH;
    int kg = (sl & ~7) | ((sl & 7) ^ (row & 7));
    load16_lds(Bw + (size_t)(h0 + row) * K + kg * 16, &Bs[(i * 256 + w * 64) * 16]);
  }
  // stage A batch 0 (rows r -> global row r*64+b)
#pragma unroll
  for (int i = 0; i < CH / 4; ++i) {
    int L = i * 256 + tid;
    int r = L / CH, sl = L % CH;
    int kg = (sl & ~7) | ((sl & 7) ^ (r & 7));
    load16_lds(A + ((size_t)r * 64 + b) * K + kg * 16, &As[(i * 256 + w * 64) * 16]);
  }
  __syncthreads();
  float beta = sbeta;
  const double DSCALE = (double)SCALE_F;
  const double DWMIN  = (double)0.001f;
  float mem = 0.0f;
  int lr = lane & 15, lk = lane >> 4;
  int arow = w * 16 + lr;
  for (int g = 0; g < 8; ++g) {
    // nbuf for this batch (wave 1; consumed by wave0's scan after the pm barrier)
    if (w == 1) {
      int t = g * 64 + lane; if (t > 499) t = 499;
      nbuf[lane] = nprev[t * 64 + b];
    }
    i32x4 acc0 = {0,0,0,0}, acc1 = {0,0,0,0}, acc2 = {0,0,0,0}, acc3 = {0,0,0,0};
#pragma unroll
    for (int ks = 0; ks < K / 64; ++ks) {
      int kc = ks * 4 + lk;
      int s0 = (kc & ~7) | ((kc & 7) ^ (lr & 7));     // shared slot (arow&7==brow&7==lr&7)
      i32x4 av  = *(const i32x4*)&As[arow * K + s0 * 16];
      i32x4 bv0 = *(const i32x4*)&Bs[(0 * 16 + lr) * K + s0 * 16];
      i32x4 bv1 = *(const i32x4*)&Bs[(1 * 16 + lr) * K + s0 * 16];
      i32x4 bv2 = *(const i32x4*)&Bs[(2 * 16 + lr) * K + s0 * 16];
      i32x4 bv3 = *(const i32x4*)&Bs[(3 * 16 + lr) * K + s0 * 16];
      acc0 = __builtin_amdgcn_mfma_i32_16x16x64_i8(av, bv0, acc0, 0, 0, 0);
      acc1 = __builtin_amdgcn_mfma_i32_16x16x64_i8(av, bv1, acc1, 0, 0, 0);
      acc2 = __builtin_amdgcn_mfma_i32_16x16x64_i8(av, bv2, acc2, 0, 0, 0);
      acc3 = __builtin_amdgcn_mfma_i32_16x16x64_i8(av, bv3, acc3, 0, 0, 0);
    }
    // pm write: D layout col=lane&15, row=(lane>>4)*4+i (verified, dtype-independent)
    int pr = w * 16 + lk * 4;
#pragma unroll
    for (int i = 0; i < 4; ++i) {
      pm[pr + i][ 0 + lr] = (uint16_t)acc0[i];
      pm[pr + i][16 + lr] = (uint16_t)acc1[i];
      pm[pr + i][32 + lr] = (uint16_t)acc2[i];
      pm[pr + i][48 + lr] = (uint16_t)acc3[i];
    }
    __syncthreads();                 // pm + nbuf ready; As consumed
    // all waves: issue next A batch (async; drains at the trailing barrier)
    if (g < 7) {
#pragma unroll
      for (int i = 0; i < CH / 4; ++i) {
        int L = i * 256 + tid;
        int r = L / CH, sl = L % CH;
        int kg = (sl & ~7) | ((sl & 7) ^ (r & 7));
        int t = (g + 1) * 64 + r; if (t > 499) t = 499;
        load16_lds(A + ((size_t)t * 64 + b) * K + kg * 16, &As[(i * 256 + w * 64) * 16]);
      }
    }
    // wave0: np-exact serial LIF over this batch's t's (col = h0+lane)
    if (w == 0) {
      int Nt = (g == 7) ? 52 : 64;   // 500 = 7*64 + 52
      for (int r = 0; r < Nt; ++r) {
        int t = g * 64 + r, row = t * 64 + b;
        float cur = (float)((double)(int)pm[r][lane] * DSCALE + (double)nbuf[r] * DWMIN);
        int   rs  = (mem > 1.0f);
        float t2  = __fadd_rn(__fmul_rn(beta, mem), cur);
        mem = rs ? __fsub_rn(t2, 1.0f) : t2;
        int spk = (mem > 1.0f);
        if (!LAST) {
          __builtin_nontemporal_store(spk ? 1.0f : 0.0f,
              &spk_out[(size_t)t * 32768 + (b << 9) + h0 + lane]);
          s_out[(size_t)row * 512 + h0 + lane] = (int8_t)spk;
          unsigned long long bal = __ballot(spk);
          if (lane == 0) atomicAdd(n_out + row, (int)__popcll(bal));
        } else if (lane < OD) {
          __builtin_nontemporal_store(spk ? 1.0f : 0.0f,
              &spk_out[(size_t)t * (BB * OD) + b * OD + lane]);
          __builtin_nontemporal_store(mem,
              &mem_out[(size_t)t * (BB * OD) + b * OD + lane]);
        }
      }
    }
    __syncthreads();                 // As[g+1] staged; pm free for overwrite
  }
}

// ---------------------------------------------------------------- launch
extern "C" void kernel_launch(void* const* d_in, const int* in_sizes, int n_in,
                              void* d_out, int out_size, void* d_ws, size_t ws_size,
                              hipStream_t stream) {
  const float* x      = (const float*)d_in[0];
  const float* Wch    = (const float*)d_in[1];
  const float* W1     = (const float*)d_in[2];
  const float* W2     = (const float*)d_in[3];
  const float* W3     = (const float*)d_in[4];
  const float* W4     = (const float*)d_in[5];
  const float* cbetas = (const float*)d_in[6];
  const float* b1     = (const float*)d_in[7];
  const float* b2     = (const float*)d_in[8];
  const float* b3     = (const float*)d_in[9];
  const float* b4     = (const float*)d_in[10];

  uint8_t* ws = (uint8_t*)d_ws;
  int8_t*   wk1   = (int8_t*)(ws + 0);          // 512*256   = 131072
  int8_t*   wk2   = (int8_t*)(ws + 131072);     // 512*512   = 262144
  int8_t*   wk3   = (int8_t*)(ws + 393216);     // 262144
  int8_t*   wk4   = (int8_t*)(ws + 655360);     // 64*512    = 32768
  int*      n_ch  = (int*)(ws + 688128);        // 32000*4 each
  int*      n1    = (int*)(ws + 816128);
  int*      n2    = (int*)(ws + 944128);
  int*      n3    = (int*)(ws + 1072128);       // ends 1200128
  int8_t*   chs   = (int8_t*)(ws + 1200128);    // 32000*256 = 8192000
  int8_t*   sbufA = (int8_t*)(ws + 9392128);    // 32000*512 = 16384000
  int8_t*   sbufB = (int8_t*)(ws + 25776128);   // 16384000 -> ends 42160128

  float* out  = (float*)d_out;
  float* spk1 = out;                // 500*64*512
  float* spk2 = out + 16384000;
  float* spk3 = out + 32768000;
  float* spk4 = out + 49152000;     // 500*64*35
  float* mem4 = out + 50272000;

  hipMemsetAsync(ws + 688128, 0, 512000, stream);

  // prep (blocks 0..2687) + cochlea (blocks 2688..2751), independent work
  k_prep_cochlea<<<2752, 256, 0, stream>>>(W1, W2, W3, W4, wk1, wk2, wk3, wk4,
                                           x, Wch, cbetas, chs, n_ch);

  // fused layers: read buffer != write buffer (in-kernel concurrent read/write)
  k_layer<256, false><<<512, 256, 0, stream>>>(chs,   wk1, n_ch, b1, spk1, sbufA, n1, nullptr);
  k_layer<512, false><<<512, 256, 0, stream>>>(sbufA, wk2, n1,   b2, spk2, sbufB, n2, nullptr);
  k_layer<512, false><<<512, 256, 0, stream>>>(sbufB, wk3, n2,   b3, spk3, sbufA, n3, nullptr);
  k_layer<512, true ><<<64,  256, 0, stream>>>(sbufA, wk4, n3,   b4, spk4, nullptr, nullptr, mem4);
}

// Round 8
// 514.547 us; speedup vs baseline: 2.9527x; 1.0755x over previous
//
#include <hip/hip_runtime.h>
#include <stdint.h>

#define TT   500
#define BB   64
#define IND  256
#define HD   512
#define OD   35

typedef __attribute__((ext_vector_type(4))) int i32x4;

// fp32 scale exactly as numpy computes it
#define SCALE_F ((float)((1.0 - 0.001) / 31.0))

__device__ __forceinline__ void load16_lds(const int8_t* g, int8_t* l) {
  __builtin_amdgcn_global_load_lds((const __attribute__((address_space(1))) void*)g,
                                   (__attribute__((address_space(3))) void*)l, 16, 0, 0);
}

// ---------------------------------------------------------------- prep + cochlea (r3 verbatim)
__global__ __launch_bounds__(256) void k_prep_cochlea(const float* __restrict__ W1,
                                                      const float* __restrict__ W2,
                                                      const float* __restrict__ W3,
                                                      const float* __restrict__ W4,
                                                      int8_t* __restrict__ wk1,
                                                      int8_t* __restrict__ wk2,
                                                      int8_t* __restrict__ wk3,
                                                      int8_t* __restrict__ wk4,
                                                      const float* __restrict__ x,
                                                      const float* __restrict__ Wch,
                                                      const float* __restrict__ cbetas,
                                                      int8_t* __restrict__ chs,
                                                      int* __restrict__ n_ch) {
  __shared__ float xs[TT];
  if (blockIdx.x < 2688) {
    int id = blockIdx.x * 256 + threadIdx.x;
    const float* W; int8_t* wk; int idx, K, H;
    if (id < 131072)       { idx = id;          W = W1; wk = wk1; K = 256; H = 512; }
    else if (id < 393216)  { idx = id - 131072; W = W2; wk = wk2; K = 512; H = 512; }
    else if (id < 655360)  { idx = id - 393216; W = W3; wk = wk3; K = 512; H = 512; }
    else                   { idx = id - 655360; W = W4; wk = wk4; K = 512; H = 35;  }
    int h = idx / K;
    int k = idx - h * K;
    int8_t bits = 0;
    if (h < H) {
      float w  = W[h * K + k];
      float wc = fminf(1.0f, fmaxf(0.001f, w));
      float v  = (wc - 0.001f) / SCALE_F;
      float q  = rintf(v);                 // round-half-even, matches np.round; 0..31
      bits = (int8_t)q;
    }
    wk[idx] = bits;
  } else {
    int b = blockIdx.x - 2688;
    int i = threadIdx.x;
    for (int t = threadIdx.x; t < TT; t += 256) xs[t] = x[b * TT + t];
    __syncthreads();
    float w    = Wch[i];
    float beta = fminf(1.0f, fmaxf(0.0f, cbetas[i]));
    float mem  = 0.0f;
    for (int t = 0; t < TT; ++t) {
      float cur = __fmul_rn(xs[t], w);
      int   rs  = (mem > 1.0f);
      float t2  = __fadd_rn(__fmul_rn(beta, mem), cur);
      mem = rs ? __fsub_rn(t2, 1.0f) : t2;
      int spk = (mem > 1.0f);
      int row = t * BB + b;
      chs[(size_t)row * IND + i] = (int8_t)spk;
      unsigned long long bal = __ballot(spk);
      if ((threadIdx.x & 63) == 0) atomicAdd(n_ch + row, (int)__popcll(bal));
    }
  }
}

// ---------------------------------------------------------------- fused layer: GEMM + LIF scan
// One block = (batch element b) x (64-col slice h0). Block decode b=blk&63 so the
// 8 slice-blocks sharing b land on one XCD -> A rows L2-resident.
// Per t-batch of 64: 4-wave i8 MFMA from swizzled LDS -> pm[64][68] u16 in LDS ->
// barrier -> all waves async-issue next A-batch stage -> wave0 runs the np-exact
// serial LIF. Scan loads are BATCHED: 4 quarters of 16, fully unrolled, 1-quarter
// lookahead (r7 regression was the unbatched ds_read in the serial chain).
template<int K, bool LAST>
__global__ __launch_bounds__(256) void k_layer(const int8_t* __restrict__ A,
                                               const int8_t* __restrict__ Bw,
                                               const int* __restrict__ nprev,
                                               const float* __restrict__ pbeta,
                                               float* __restrict__ spk_out,
                                               int8_t* __restrict__ s_out,
                                               int* __restrict__ n_out,
                                               float* __restrict__ mem_out) {
  constexpr int CH = K / 16;                 // 16-B chunks per row (32 or 16)
  __shared__ __align__(16) int8_t Bs[64 * K];
  __shared__ __align__(16) int8_t As[64 * K];
  __shared__ uint16_t pm[64][68];            // +4 pad: conflict-free write/read
  __shared__ int nbuf[64];
  __shared__ float sbeta;
  int tid = threadIdx.x, lane = tid & 63, w = tid >> 6;
  int b, h0;
  if (LAST) { b = blockIdx.x;      h0 = 0; }
  else      { b = blockIdx.x & 63; h0 = (blockIdx.x >> 6) * 64; }
  if (tid == 0) sbeta = fminf(1.0f, fmaxf(0.0f, *pbeta));
  // stage B slice [64][K], XOR-swizzled (slot sl holds chunk (sl&~7)|((sl&7)^(row&7)))
#pragma unroll
  for (int i = 0; i < CH / 4; ++i) {
    int L = i * 256 + tid;
    int row = L / CH, sl = L % CH;
    int kg = (sl & ~7) | ((sl & 7) ^ (row & 7));
    load16_lds(Bw + (size_t)(h0 + row) * K + kg * 16, &Bs[(i * 256 + w * 64) * 16]);
  }
  // stage A batch 0 (rows r -> global row r*64+b)
#pragma unroll
  for (int i = 0; i < CH / 4; ++i) {
    int L = i * 256 + tid;
    int r = L / CH, sl = L % CH;
    int kg = (sl & ~7) | ((sl & 7) ^ (r & 7));
    load16_lds(A + ((size_t)r * 64 + b) * K + kg * 16, &As[(i * 256 + w * 64) * 16]);
  }
  __syncthreads();
  float beta = sbeta;
  const double DSCALE = (double)SCALE_F;
  const double DWMIN  = (double)0.001f;
  float mem = 0.0f;
  int lr = lane & 15, lk = lane >> 4;
  int arow = w * 16 + lr;
  for (int g = 0; g < 8; ++g) {
    // nbuf for this batch (wave 1; consumed by wave0's scan after the pm barrier)
    if (w == 1) {
      int t = g * 64 + lane; if (t > 499) t = 499;
      nbuf[lane] = nprev[t * 64 + b];
    }
    i32x4 acc0 = {0,0,0,0}, acc1 = {0,0,0,0}, acc2 = {0,0,0,0}, acc3 = {0,0,0,0};
#pragma unroll
    for (int ks = 0; ks < K / 64; ++ks) {
      int kc = ks * 4 + lk;
      int s0 = (kc & ~7) | ((kc & 7) ^ (lr & 7));     // shared slot (arow&7==brow&7==lr&7)
      i32x4 av  = *(const i32x4*)&As[arow * K + s0 * 16];
      i32x4 bv0 = *(const i32x4*)&Bs[(0 * 16 + lr) * K + s0 * 16];
      i32x4 bv1 = *(const i32x4*)&Bs[(1 * 16 + lr) * K + s0 * 16];
      i32x4 bv2 = *(const i32x4*)&Bs[(2 * 16 + lr) * K + s0 * 16];
      i32x4 bv3 = *(const i32x4*)&Bs[(3 * 16 + lr) * K + s0 * 16];
      acc0 = __builtin_amdgcn_mfma_i32_16x16x64_i8(av, bv0, acc0, 0, 0, 0);
      acc1 = __builtin_amdgcn_mfma_i32_16x16x64_i8(av, bv1, acc1, 0, 0, 0);
      acc2 = __builtin_amdgcn_mfma_i32_16x16x64_i8(av, bv2, acc2, 0, 0, 0);
      acc3 = __builtin_amdgcn_mfma_i32_16x16x64_i8(av, bv3, acc3, 0, 0, 0);
    }
    // pm write: D layout col=lane&15, row=(lane>>4)*4+i (verified, dtype-independent)
    int pr = w * 16 + lk * 4;
#pragma unroll
    for (int i = 0; i < 4; ++i) {
      pm[pr + i][ 0 + lr] = (uint16_t)acc0[i];
      pm[pr + i][16 + lr] = (uint16_t)acc1[i];
      pm[pr + i][32 + lr] = (uint16_t)acc2[i];
      pm[pr + i][48 + lr] = (uint16_t)acc3[i];
    }
    __syncthreads();                 // pm + nbuf ready; As consumed
    // all waves: issue next A batch (async; drains at the trailing barrier)
    if (g < 7) {
#pragma unroll
      for (int i = 0; i < CH / 4; ++i) {
        int L = i * 256 + tid;
        int r = L / CH, sl = L % CH;
        int kg = (sl & ~7) | ((sl & 7) ^ (r & 7));
        int t = (g + 1) * 64 + r; if (t > 499) t = 499;
        load16_lds(A + ((size_t)t * 64 + b) * K + kg * 16, &As[(i * 256 + w * 64) * 16]);
      }
    }
    // wave0: np-exact serial LIF, quarters of 16 with 1-quarter load lookahead.
    // Uniform 64-step chain every batch (pm rows >=52 of batch 7 hold clamped-row
    // GEMM output, well-defined); stores predicated on t<500 (uniform branch).
    if (w == 0) {
      float curA[16], curB[16];
#define LOADQ(dst, q)                                                         \
      { _Pragma("unroll") for (int r = 0; r < 16; ++r) {                      \
          int rr = (q) * 16 + r;                                              \
          dst[r] = (float)((double)(int)pm[rr][lane] * DSCALE                 \
                           + (double)nbuf[rr] * DWMIN); } }
#define CHAINQ(src, q)                                                        \
      { _Pragma("unroll") for (int r = 0; r < 16; ++r) {                      \
          int t = g * 64 + (q) * 16 + r;                                      \
          int   rs = (mem > 1.0f);                                            \
          float t2 = __fadd_rn(__fmul_rn(beta, mem), src[r]);                 \
          mem = rs ? __fsub_rn(t2, 1.0f) : t2;                                \
          int spk = (mem > 1.0f);                                             \
          if (t < 500) {                                                      \
            int row = t * 64 + b;                                             \
            if (!LAST) {                                                      \
              __builtin_nontemporal_store(spk ? 1.0f : 0.0f,                  \
                  &spk_out[(size_t)t * 32768 + (b << 9) + h0 + lane]);        \
              s_out[(size_t)row * 512 + h0 + lane] = (int8_t)spk;             \
              unsigned long long bal = __ballot(spk);                         \
              if (lane == 0) atomicAdd(n_out + row, (int)__popcll(bal));      \
            } else if (lane < OD) {                                           \
              __builtin_nontemporal_store(spk ? 1.0f : 0.0f,                  \
                  &spk_out[(size_t)t * (BB * OD) + b * OD + lane]);           \
              __builtin_nontemporal_store(mem,                                \
                  &mem_out[(size_t)t * (BB * OD) + b * OD + lane]);           \
            }                                                                 \
          } } }
      LOADQ(curA, 0)
      LOADQ(curB, 1)
      CHAINQ(curA, 0)
      LOADQ(curA, 2)
      CHAINQ(curB, 1)
      LOADQ(curB, 3)
      CHAINQ(curA, 2)
      CHAINQ(curB, 3)
#undef LOADQ
#undef CHAINQ
    }
    __syncthreads();                 // As[g+1] staged; pm free for overwrite
  }
}

// ---------------------------------------------------------------- launch
extern "C" void kernel_launch(void* const* d_in, const int* in_sizes, int n_in,
                              void* d_out, int out_size, void* d_ws, size_t ws_size,
                              hipStream_t stream) {
  const float* x      = (const float*)d_in[0];
  const float* Wch    = (const float*)d_in[1];
  const float* W1     = (const float*)d_in[2];
  const float* W2     = (const float*)d_in[3];
  const float* W3     = (const float*)d_in[4];
  const float* W4     = (const float*)d_in[5];
  const float* cbetas = (const float*)d_in[6];
  const float* b1     = (const float*)d_in[7];
  const float* b2     = (const float*)d_in[8];
  const float* b3     = (const float*)d_in[9];
  const float* b4     = (const float*)d_in[10];

  uint8_t* ws = (uint8_t*)d_ws;
  int8_t*   wk1   = (int8_t*)(ws + 0);          // 512*256   = 131072
  int8_t*   wk2   = (int8_t*)(ws + 131072);     // 512*512   = 262144
  int8_t*   wk3   = (int8_t*)(ws + 393216);     // 262144
  int8_t*   wk4   = (int8_t*)(ws + 655360);     // 64*512    = 32768
  int*      n_ch  = (int*)(ws + 688128);        // 32000*4 each
  int*      n1    = (int*)(ws + 816128);
  int*      n2    = (int*)(ws + 944128);
  int*      n3    = (int*)(ws + 1072128);       // ends 1200128
  int8_t*   chs   = (int8_t*)(ws + 1200128);    // 32000*256 = 8192000
  int8_t*   sbufA = (int8_t*)(ws + 9392128);    // 32000*512 = 16384000
  int8_t*   sbufB = (int8_t*)(ws + 25776128);   // 16384000 -> ends 42160128

  float* out  = (float*)d_out;
  float* spk1 = out;                // 500*64*512
  float* spk2 = out + 16384000;
  float* spk3 = out + 32768000;
  float* spk4 = out + 49152000;     // 500*64*35
  float* mem4 = out + 50272000;

  hipMemsetAsync(ws + 688128, 0, 512000, stream);

  // prep (blocks 0..2687) + cochlea (blocks 2688..2751), independent work
  k_prep_cochlea<<<2752, 256, 0, stream>>>(W1, W2, W3, W4, wk1, wk2, wk3, wk4,
                                           x, Wch, cbetas, chs, n_ch);

  // fused layers: read buffer != write buffer (in-kernel concurrent read/write)
  k_layer<256, false><<<512, 256, 0, stream>>>(chs,   wk1, n_ch, b1, spk1, sbufA, n1, nullptr);
  k_layer<512, false><<<512, 256, 0, stream>>>(sbufA, wk2, n1,   b2, spk2, sbufB, n2, nullptr);
  k_layer<512, false><<<512, 256, 0, stream>>>(sbufB, wk3, n2,   b3, spk3, sbufA, n3, nullptr);
  k_layer<512, true ><<<64,  256, 0, stream>>>(sbufA, wk4, n3,   b4, spk4, nullptr, nullptr, mem4);
}